// Round 3
// baseline (197.277 us; speedup 1.0000x reference)
//
#include <hip/hip_runtime.h>
#include <math.h>

#define IN_NODES  4096
#define OUT_NODES 1024
#define ROW_ELEMS (OUT_NODES * 16)     // 16384 floats per in-node slice
#define ROW_C4    (ROW_ELEMS / 4)      // 4096 float4-chunks per in-node

typedef unsigned short u16;
typedef unsigned int   u32;

__device__ __forceinline__ float dot4(const float4 a, const float4 b) {
    return a.x*b.x + a.y*b.y + a.z*b.z + a.w*b.w;
}
__device__ __forceinline__ void fma4(float4& a, const float c, const float4 u) {
    a.x += c*u.x; a.y += c*u.y; a.z += c*u.z; a.w += c*u.w;
}
__device__ __forceinline__ void add4(float4& a, const float4 u) {
    a.x += u.x; a.y += u.y; a.z += u.z; a.w += u.w;
}
__device__ __forceinline__ float b2f1(u16 u) {
    return __uint_as_float(((u32)u) << 16);
}
__device__ __forceinline__ float4 b2f(ushort4 u) {
    return make_float4(b2f1(u.x), b2f1(u.y), b2f1(u.z), b2f1(u.w));
}
__device__ __forceinline__ u16 f2b(float x) {            // RNE f32->bf16
    u32 b = __float_as_uint(x);
    return (u16)((b + 0x7FFFu + ((b >> 16) & 1u)) >> 16);
}
__device__ __forceinline__ ushort4 f2b4(float4 v) {
    ushort4 r; r.x = f2b(v.x); r.y = f2b(v.y); r.z = f2b(v.z); r.w = f2b(v.w);
    return r;
}

// ---------------------------------------------------------------------------
// Iteration 1: c is uniform (b==0). Streaming reduce of uh; optionally also
// emits a bf16 copy of uh for the later passes. Coalesced chunk ownership:
// thread t=(wave,lane) owns float4-chunks c4 = wave*256 + j*64 + lane, j=0..3.
// ---------------------------------------------------------------------------
template <bool WBF16>
__global__ __launch_bounds__(1024) void route_uniform(const float* __restrict__ uh,
                                                      float* __restrict__ s_partial,
                                                      u16* __restrict__ uh2,
                                                      int per_block) {
    const int t  = threadIdx.x;
    const int c4 = ((t >> 6) << 8) + (t & 63);

    float4 a0 = make_float4(0.f,0.f,0.f,0.f), a1 = a0, a2 = a0, a3 = a0;

    const int i0 = blockIdx.x * per_block;
    const float4* p = reinterpret_cast<const float4*>(uh) + (size_t)i0 * ROW_C4 + c4;
    ushort4*      q = reinterpret_cast<ushort4*>(uh2)     + (size_t)i0 * ROW_C4 + c4;

    for (int g = 0; g < per_block; ++g) {
        float4 u0 = p[0], u1 = p[64], u2 = p[128], u3 = p[192];
        add4(a0, u0); add4(a1, u1); add4(a2, u2); add4(a3, u3);
        if (WBF16) {
            q[0]   = f2b4(u0); q[64]  = f2b4(u1);
            q[128] = f2b4(u2); q[192] = f2b4(u3);
            q += ROW_C4;
        }
        p += ROW_C4;
    }

    const float c = 1.0f / OUT_NODES;
    a0.x*=c; a0.y*=c; a0.z*=c; a0.w*=c;
    a1.x*=c; a1.y*=c; a1.z*=c; a1.w*=c;
    a2.x*=c; a2.y*=c; a2.z*=c; a2.w*=c;
    a3.x*=c; a3.y*=c; a3.z*=c; a3.w*=c;

    float4* sp = reinterpret_cast<float4*>(s_partial) + (size_t)blockIdx.x * ROW_C4 + c4;
    sp[0] = a0; sp[64] = a1; sp[128] = a2; sp[192] = a3;
}

// ---------------------------------------------------------------------------
// Softmax pass reading the bf16 copy. Same ownership; out-node o = c4>>2 lives
// in a 4-lane quad -> quad shfl reduce for d[o]. Block sum (2 barriers) per
// 2 in-nodes; distance-2 in-node prefetch keeps loads in flight across the
// barriers. No max-subtraction: |d| <= |V|*~4sigma < ~10, exp is safe in f32.
// ---------------------------------------------------------------------------
__global__ __launch_bounds__(1024) void route_soft_bf16(const u16* __restrict__ uh2,
                                                        const float* __restrict__ V,
                                                        float* __restrict__ s_partial,
                                                        int per_block) {
    const int t    = threadIdx.x;
    const int wave = t >> 6;
    const int lane = t & 63;
    const int c4   = (wave << 8) + lane;

    __shared__ float2 redw[16];
    __shared__ float2 redS;

    const float4* vp = reinterpret_cast<const float4*>(V) + c4;
    const float4 v0 = vp[0], v1 = vp[64], v2 = vp[128], v3 = vp[192];

    float4 a0 = make_float4(0.f,0.f,0.f,0.f), a1 = a0, a2 = a0, a3 = a0;

    const ushort4* p = reinterpret_cast<const ushort4*>(uh2)
                     + (size_t)(blockIdx.x * per_block) * ROW_C4 + c4;

    ushort4 ca0 = p[0], ca1 = p[64], ca2 = p[128], ca3 = p[192];
    const ushort4* pb = p + ROW_C4;
    ushort4 cb0 = pb[0], cb1 = pb[64], cb2 = pb[128], cb3 = pb[192];

    for (int g = 0; g < per_block; g += 2) {
        ushort4 na0, na1, na2, na3, nb0, nb1, nb2, nb3;
        const ushort4* pn = p + 2 * ROW_C4;
        if (g + 2 < per_block) {
            na0 = pn[0]; na1 = pn[64]; na2 = pn[128]; na3 = pn[192];
            const ushort4* pn2 = pn + ROW_C4;
            nb0 = pn2[0]; nb1 = pn2[64]; nb2 = pn2[128]; nb3 = pn2[192];
        }

        const float4 fa0 = b2f(ca0), fa1 = b2f(ca1), fa2 = b2f(ca2), fa3 = b2f(ca3);
        const float4 fb0 = b2f(cb0), fb1 = b2f(cb1), fb2 = b2f(cb2), fb3 = b2f(cb3);

        float da0 = dot4(fa0, v0), da1 = dot4(fa1, v1),
              da2 = dot4(fa2, v2), da3 = dot4(fa3, v3);
        float db0 = dot4(fb0, v0), db1 = dot4(fb1, v1),
              db2 = dot4(fb2, v2), db3 = dot4(fb3, v3);

        da0 += __shfl_xor(da0, 1); da0 += __shfl_xor(da0, 2);
        da1 += __shfl_xor(da1, 1); da1 += __shfl_xor(da1, 2);
        da2 += __shfl_xor(da2, 1); da2 += __shfl_xor(da2, 2);
        da3 += __shfl_xor(da3, 1); da3 += __shfl_xor(da3, 2);
        db0 += __shfl_xor(db0, 1); db0 += __shfl_xor(db0, 2);
        db1 += __shfl_xor(db1, 1); db1 += __shfl_xor(db1, 2);
        db2 += __shfl_xor(db2, 1); db2 += __shfl_xor(db2, 2);
        db3 += __shfl_xor(db3, 1); db3 += __shfl_xor(db3, 2);

        float ea0 = __expf(da0), ea1 = __expf(da1),
              ea2 = __expf(da2), ea3 = __expf(da3);
        float eb0 = __expf(db0), eb1 = __expf(db1),
              eb2 = __expf(db2), eb3 = __expf(db3);

        // block sum; each out-node counted 4x by its quad -> scale by 4 later
        float sx = (ea0 + ea1) + (ea2 + ea3);
        float sy = (eb0 + eb1) + (eb2 + eb3);
        #pragma unroll
        for (int off = 32; off; off >>= 1) {
            sx += __shfl_xor(sx, off);
            sy += __shfl_xor(sy, off);
        }
        if (lane == 0) redw[wave] = make_float2(sx, sy);
        __syncthreads();
        if (wave == 0) {
            float2 qv = (lane < 16) ? redw[lane] : make_float2(0.f, 0.f);
            #pragma unroll
            for (int off = 8; off; off >>= 1) {
                qv.x += __shfl_xor(qv.x, off);
                qv.y += __shfl_xor(qv.y, off);
            }
            if (lane == 0) redS = qv;
        }
        __syncthreads();
        const float inva = 4.0f / redS.x;
        const float invb = 4.0f / redS.y;

        fma4(a0, ea0 * inva, fa0); fma4(a0, eb0 * invb, fb0);
        fma4(a1, ea1 * inva, fa1); fma4(a1, eb1 * invb, fb1);
        fma4(a2, ea2 * inva, fa2); fma4(a2, eb2 * invb, fb2);
        fma4(a3, ea3 * inva, fa3); fma4(a3, eb3 * invb, fb3);

        ca0 = na0; ca1 = na1; ca2 = na2; ca3 = na3;
        cb0 = nb0; cb1 = nb1; cb2 = nb2; cb3 = nb3;
        p = pn;
    }

    float4* sp = reinterpret_cast<float4*>(s_partial) + (size_t)blockIdx.x * ROW_C4 + c4;
    sp[0] = a0; sp[64] = a1; sp[128] = a2; sp[192] = a3;
}

// ---------------------------------------------------------------------------
// Fallback f32 softmax pass (used only if workspace is too small for uh2).
// ---------------------------------------------------------------------------
__global__ __launch_bounds__(1024) void route_soft_f32(const float* __restrict__ uh,
                                                       const float* __restrict__ V,
                                                       float* __restrict__ s_partial,
                                                       int per_block) {
    const int t    = threadIdx.x;
    const int wave = t >> 6;
    const int lane = t & 63;
    const int c4   = (wave << 8) + lane;

    __shared__ float2 redw[16];
    __shared__ float2 redS;

    const float4* vp = reinterpret_cast<const float4*>(V) + c4;
    const float4 v0 = vp[0], v1 = vp[64], v2 = vp[128], v3 = vp[192];

    float4 a0 = make_float4(0.f,0.f,0.f,0.f), a1 = a0, a2 = a0, a3 = a0;

    const int i0 = blockIdx.x * per_block;
    for (int g = 0; g < per_block; g += 2) {
        const float4* pa = reinterpret_cast<const float4*>(uh)
                         + (size_t)(i0 + g) * ROW_C4 + c4;
        const float4* pb = pa + ROW_C4;
        float4 ua0 = pa[0], ua1 = pa[64], ua2 = pa[128], ua3 = pa[192];
        float4 ub0 = pb[0], ub1 = pb[64], ub2 = pb[128], ub3 = pb[192];

        float da0 = dot4(ua0, v0), da1 = dot4(ua1, v1),
              da2 = dot4(ua2, v2), da3 = dot4(ua3, v3);
        float db0 = dot4(ub0, v0), db1 = dot4(ub1, v1),
              db2 = dot4(ub2, v2), db3 = dot4(ub3, v3);

        da0 += __shfl_xor(da0, 1); da0 += __shfl_xor(da0, 2);
        da1 += __shfl_xor(da1, 1); da1 += __shfl_xor(da1, 2);
        da2 += __shfl_xor(da2, 1); da2 += __shfl_xor(da2, 2);
        da3 += __shfl_xor(da3, 1); da3 += __shfl_xor(da3, 2);
        db0 += __shfl_xor(db0, 1); db0 += __shfl_xor(db0, 2);
        db1 += __shfl_xor(db1, 1); db1 += __shfl_xor(db1, 2);
        db2 += __shfl_xor(db2, 1); db2 += __shfl_xor(db2, 2);
        db3 += __shfl_xor(db3, 1); db3 += __shfl_xor(db3, 2);

        float ea0 = __expf(da0), ea1 = __expf(da1),
              ea2 = __expf(da2), ea3 = __expf(da3);
        float eb0 = __expf(db0), eb1 = __expf(db1),
              eb2 = __expf(db2), eb3 = __expf(db3);

        float sx = (ea0 + ea1) + (ea2 + ea3);
        float sy = (eb0 + eb1) + (eb2 + eb3);
        #pragma unroll
        for (int off = 32; off; off >>= 1) {
            sx += __shfl_xor(sx, off);
            sy += __shfl_xor(sy, off);
        }
        if (lane == 0) redw[wave] = make_float2(sx, sy);
        __syncthreads();
        if (wave == 0) {
            float2 qv = (lane < 16) ? redw[lane] : make_float2(0.f, 0.f);
            #pragma unroll
            for (int off = 8; off; off >>= 1) {
                qv.x += __shfl_xor(qv.x, off);
                qv.y += __shfl_xor(qv.y, off);
            }
            if (lane == 0) redS = qv;
        }
        __syncthreads();
        const float inva = 4.0f / redS.x;
        const float invb = 4.0f / redS.y;

        fma4(a0, ea0 * inva, ua0); fma4(a0, eb0 * invb, ub0);
        fma4(a1, ea1 * inva, ua1); fma4(a1, eb1 * invb, ub1);
        fma4(a2, ea2 * inva, ua2); fma4(a2, eb2 * invb, ub2);
        fma4(a3, ea3 * inva, ua3); fma4(a3, eb3 * invb, ub3);
    }

    float4* sp = reinterpret_cast<float4*>(s_partial) + (size_t)blockIdx.x * ROW_C4 + c4;
    sp[0] = a0; sp[64] = a1; sp[128] = a2; sp[192] = a3;
}

// ---------------------------------------------------------------------------
// Reduce partials -> s, squash -> v, write v to out, update cumulative V.
// Grid = 64 x 256; global thread index == o*16 + f.
// ---------------------------------------------------------------------------
__global__ __launch_bounds__(256) void reduce_squash(const float* __restrict__ s_partial,
                                                     float* __restrict__ V,
                                                     float* __restrict__ out,
                                                     int nblk, int first) {
    const int gidx = blockIdx.x * 256 + threadIdx.x;
    float s0 = 0.f, s1 = 0.f, s2 = 0.f, s3 = 0.f;
    int b = 0;
    for (; b + 3 < nblk; b += 4) {
        s0 += s_partial[(size_t)(b    ) * ROW_ELEMS + gidx];
        s1 += s_partial[(size_t)(b + 1) * ROW_ELEMS + gidx];
        s2 += s_partial[(size_t)(b + 2) * ROW_ELEMS + gidx];
        s3 += s_partial[(size_t)(b + 3) * ROW_ELEMS + gidx];
    }
    for (; b < nblk; ++b)
        s0 += s_partial[(size_t)b * ROW_ELEMS + gidx];
    float s = (s0 + s1) + (s2 + s3);

    float sq = s * s;
    #pragma unroll
    for (int m = 8; m; m >>= 1)
        sq += __shfl_xor(sq, m);

    float scale = sq / ((1.0f + sq) * sqrtf(sq));
    float v = s * scale;

    out[gidx] = v;
    V[gidx]   = first ? v : (V[gidx] + v);
}

// ---------------------------------------------------------------------------
extern "C" void kernel_launch(void* const* d_in, const int* in_sizes, int n_in,
                              void* d_out, int out_size, void* d_ws, size_t ws_size,
                              hipStream_t stream) {
    const float* uh  = (const float*)d_in[0];
    float*       out = (float*)d_out;

    char*  ws   = (char*)d_ws;
    float* V    = (float*)ws;                    // 64 KB
    float* part = (float*)(ws + 65536);          // G * 64 KB

    int G = 256;
    // bf16 path needs 64KB + 256*64KB + 128MB
    const size_t need_bf16 = 65536ull * 257ull + (size_t)IN_NODES * ROW_ELEMS * 2ull;
    const bool use_bf16 = (ws_size >= need_bf16);

    if (use_bf16) {
        u16* uh2 = (u16*)(ws + 65536ull * 257ull);
        const int per_block = IN_NODES / G;      // 16

        route_uniform<true><<<G, 1024, 0, stream>>>(uh, part, uh2, per_block);
        reduce_squash<<<64, 256, 0, stream>>>(part, V, out, G, 1);

        for (int it = 1; it < 3; ++it) {
            route_soft_bf16<<<G, 1024, 0, stream>>>(uh2, V, part, per_block);
            reduce_squash<<<64, 256, 0, stream>>>(part, V, out, G, 0);
        }
    } else {
        while (G > 1 && ws_size < 65536ull * (size_t)(G + 1)) G >>= 1;
        const int per_block = IN_NODES / G;

        route_uniform<false><<<G, 1024, 0, stream>>>(uh, part, nullptr, per_block);
        reduce_squash<<<64, 256, 0, stream>>>(part, V, out, G, 1);

        for (int it = 1; it < 3; ++it) {
            route_soft_f32<<<G, 1024, 0, stream>>>(uh, V, part, per_block);
            reduce_squash<<<64, 256, 0, stream>>>(part, V, out, G, 0);
        }
    }
}